// Round 12
// baseline (37033.600 us; speedup 1.0000x reference)
//
#include <hip/hip_runtime.h>
#include <math.h>
#include <stdint.h>

// BiLSTMModel: char-LSTM (MFMA bf16) -> 2x BiLSTM scans (fused x2h) -> FCs.
// r12 = r11 (proven 13.94ms) with the 4 x2h GEMMs FUSED into the scans:
//   thread (row8,klane) holds its Wih[R] k-slice as packed bf16 in VGPRs;
//   u[p] (word_emb / concat(H0)) is prefetched 2 steps ahead into a
//   bank-swizzled LDS buffer; xpart computed during the poll-wait slack and
//   seeds the existing klane shuffle reduce. Ring protocol identical to r7.
// Removes 4 dispatches + 96MB X traffic. Scan sync untouched (1.59us/step).

#define NPOS 4096

typedef short short8 __attribute__((ext_vector_type(8)));
typedef float f32x4 __attribute__((ext_vector_type(4)));

__device__ __forceinline__ float sigf(float x) { return 1.0f / (1.0f + __expf(-x)); }
__device__ __forceinline__ float tanh_fast(float x) {
  float e = __expf(2.f * x);
  return 1.f - 2.f / (e + 1.f);   // exact at +-inf, NaN-free
}
__device__ __forceinline__ unsigned int pack_bf16(float a, float b) {
  unsigned int ua = __float_as_uint(a), ub = __float_as_uint(b);
  ua = (ua + 0x7fffu + ((ua >> 16) & 1u)) >> 16;   // RNE
  ub = (ub + 0x7fffu + ((ub >> 16) & 1u)) >> 16;
  return ua | (ub << 16);
}
__device__ __forceinline__ unsigned short bf16_1(float a) {
  unsigned int ua = __float_as_uint(a);
  return (unsigned short)((ua + 0x7fffu + ((ua >> 16) & 1u)) >> 16);
}
__device__ __forceinline__ float bf2f(unsigned short s) {
  return __uint_as_float(((unsigned int)s) << 16);
}

// ---------------- build concat char weight, bf16: Wc[g][k] (g<1024, k<512)
__global__ __launch_bounds__(256) void build_wc_kernel(
    const float* __restrict__ cWih, const float* __restrict__ cWhh,
    unsigned int* __restrict__ Wc)   // as u32 bf16-pairs: [1024][256]
{
  const int idx = blockIdx.x * 256 + threadIdx.x;
  const int g = idx >> 8;
  const int k = (idx & 255) * 2;
  const float* src = (k < 256) ? (cWih + (size_t)g * 256 + k)
                               : (cWhh + (size_t)g * 256 + (k - 256));
  Wc[idx] = pack_bf16(src[0], src[1]);
}

// ---------------- char LSTM v3 (MFMA, validated r11): 128 blocks x 32 words
__global__ __launch_bounds__(256) void mfchar_kernel(
    const int* __restrict__ chars, const int* __restrict__ lens,
    const float* __restrict__ table, const unsigned short* __restrict__ Wc,
    const float* __restrict__ cb, float* __restrict__ word_emb)
{
  __shared__ unsigned short uL[32][520];
  __shared__ unsigned short gL[32][1032];
  __shared__ int sidx[32];
  const int tid = threadIdx.x;
  const int lane = tid & 63;
  const int wv = tid >> 6;
  const int w0 = blockIdx.x * 32;
  if (tid < 32) { int l = lens[w0 + tid]; sidx[tid] = (l < 1 ? 1 : l) - 1; }
  for (int i = tid; i < 32 * 256; i += 256) uL[i >> 8][256 + (i & 255)] = 0;

  float bz[16];
  #pragma unroll
  for (int ni = 0; ni < 16; ++ni) bz[ni] = cb[wv * 256 + ni * 16 + (lane & 15)];

  float c[32];
  #pragma unroll
  for (int w = 0; w < 32; ++w) c[w] = 0.f;

  const int arow = lane & 15;
  const int akk = (lane >> 4) * 8;

  for (int t = 0; t < 16; ++t) {
    for (int w = 0; w < 32; ++w) {
      const int cid = chars[(w0 + w) * 16 + t];
      uL[w][tid] = bf16_1(table[(size_t)cid * 256 + tid]);
    }
    __syncthreads();

    f32x4 acc[2][16];
    #pragma unroll
    for (int mi = 0; mi < 2; ++mi)
      #pragma unroll
      for (int ni = 0; ni < 16; ++ni)
        acc[mi][ni] = (f32x4){bz[ni], bz[ni], bz[ni], bz[ni]};
    for (int kt = 0; kt < 16; ++kt) {
      short8 af0 = *(const short8*)&uL[arow][kt * 32 + akk];
      short8 af1 = *(const short8*)&uL[16 + arow][kt * 32 + akk];
      #pragma unroll
      for (int ni = 0; ni < 16; ++ni) {
        const unsigned short* bp =
            Wc + (size_t)(wv * 256 + ni * 16 + arow) * 512 + kt * 32 + akk;
        short8 bf = *(const short8*)bp;
        acc[0][ni] = __builtin_amdgcn_mfma_f32_16x16x32_bf16(af0, bf, acc[0][ni], 0, 0, 0);
        acc[1][ni] = __builtin_amdgcn_mfma_f32_16x16x32_bf16(af1, bf, acc[1][ni], 0, 0, 0);
      }
    }
    #pragma unroll
    for (int mi = 0; mi < 2; ++mi)
      #pragma unroll
      for (int ni = 0; ni < 16; ++ni) {
        const int col = wv * 256 + ni * 16 + (lane & 15);
        #pragma unroll
        for (int r = 0; r < 4; ++r) {
          const int row = mi * 16 + (lane >> 4) * 4 + r;
          gL[row][col] = bf16_1(acc[mi][ni][r]);
        }
      }
    __syncthreads();

    const int j = tid;
    #pragma unroll 4
    for (int w = 0; w < 32; ++w) {
      const float iv = sigf(bf2f(gL[w][j]));
      const float fv = sigf(bf2f(gL[w][256 + j]));
      const float gv = tanh_fast(bf2f(gL[w][512 + j]));
      const float ov = sigf(bf2f(gL[w][768 + j]));
      c[w] = fv * c[w] + iv * gv;
      const float h = ov * tanh_fast(c[w]);
      uL[w][256 + j] = bf16_1(h);
      if (t == sidx[w]) word_emb[(size_t)(w0 + w) * 256 + j] = h;
    }
    __syncthreads();
  }
}

// ---------------- fp32 GEMM (fc2 only): C = A @ B^T + bias
#define SW(c) ((c) + (((c) >> 3) << 2))
template <int SPLIT, int ACT>
__global__ __launch_bounds__(256) void gemm_kernel(
    const float* __restrict__ A, const float* __restrict__ A2,
    const float* __restrict__ B, const float* __restrict__ bias,
    float* __restrict__ C, int M, int N, int K)
{
  __shared__ float At[8 * 192];
  __shared__ float Bt[8 * 192];
  const int tid = threadIdx.x;
  const int bm0 = blockIdx.x * 128, bn0 = blockIdx.y * 128;
  float acc[8][8];
  #pragma unroll
  for (int i = 0; i < 8; ++i)
    #pragma unroll
    for (int j = 0; j < 8; ++j) acc[i][j] = 0.f;
  const int sr = tid >> 1;
  const int sk = (tid & 1) * 4;
  const int tm = (tid >> 4) * 8, tn = (tid & 15) * 8;
  const int swsr = SW(sr);
  const int stm = SW(tm), stn = SW(tn);
  for (int k0 = 0; k0 < K; k0 += 8) {
    const int kg = k0 + sk;
    float4 av;
    if (SPLIT) {
      const float* srcp = (kg < 512) ? A : A2;
      av = *(const float4*)(srcp + (size_t)(bm0 + sr) * 512 + (kg & 511));
    } else {
      av = *(const float4*)(A + (size_t)(bm0 + sr) * K + kg);
    }
    float4 bv = {0.f, 0.f, 0.f, 0.f};
    if (bn0 + sr < N) bv = *(const float4*)(B + (size_t)(bn0 + sr) * K + kg);
    At[(sk + 0) * 192 + swsr] = av.x; At[(sk + 1) * 192 + swsr] = av.y;
    At[(sk + 2) * 192 + swsr] = av.z; At[(sk + 3) * 192 + swsr] = av.w;
    Bt[(sk + 0) * 192 + swsr] = bv.x; Bt[(sk + 1) * 192 + swsr] = bv.y;
    Bt[(sk + 2) * 192 + swsr] = bv.z; Bt[(sk + 3) * 192 + swsr] = bv.w;
    __syncthreads();
    #pragma unroll
    for (int kk = 0; kk < 8; ++kk) {
      float a[8], b[8];
      *(float4*)&a[0] = *(const float4*)&At[kk * 192 + stm];
      *(float4*)&a[4] = *(const float4*)&At[kk * 192 + stm + 4];
      *(float4*)&b[0] = *(const float4*)&Bt[kk * 192 + stn];
      *(float4*)&b[4] = *(const float4*)&Bt[kk * 192 + stn + 4];
      #pragma unroll
      for (int i = 0; i < 8; ++i)
        #pragma unroll
        for (int j = 0; j < 8; ++j) acc[i][j] = fmaf(a[i], b[j], acc[i][j]);
    }
    __syncthreads();
  }
  #pragma unroll
  for (int i = 0; i < 8; ++i) {
    const int m = bm0 + tm + i;
    float* crow = C + (size_t)m * N;
    #pragma unroll
    for (int j = 0; j < 8; ++j) {
      const int n = bn0 + tn + j;
      if (n < N) {
        float v = acc[i][j] + bias[n];
        if (ACT) v = tanhf(v);
        crow[n] = v;
      }
    }
  }
}

// ---------------- MFMA bf16 GEMM (fc1 only, validated r10)
template <int SPLIT, int ACT>
__global__ __launch_bounds__(256) void mfgemm_kernel(
    const float* __restrict__ A, const float* __restrict__ A2,
    const float* __restrict__ B, const float* __restrict__ bias,
    float* __restrict__ C, int M, int N, int K)
{
  __shared__ unsigned short AL[128 * 40];
  __shared__ unsigned short BL[128 * 40];
  const int tid = threadIdx.x;
  const int bm0 = blockIdx.x * 128, bn0 = blockIdx.y * 128;
  const int srow = tid >> 1;
  const int sk = (tid & 1) * 16;
  const int lane = tid & 63;
  const int wid = tid >> 6;
  const int wm0 = (wid >> 1) * 64;
  const int wn0 = (wid & 1) * 64;
  const int lrow = lane & 15;
  const int lk = (lane >> 4) * 8;

  f32x4 acc[4][4];
  #pragma unroll
  for (int i = 0; i < 4; ++i)
    #pragma unroll
    for (int j = 0; j < 4; ++j) acc[i][j] = (f32x4){0.f, 0.f, 0.f, 0.f};

  for (int k0 = 0; k0 < K; k0 += 32) {
    const int kg = k0 + sk;
    float av[16], bv[16];
    if (SPLIT) {
      const float* srcp = (kg < 512) ? A : A2;
      const float* ap = srcp + (size_t)(bm0 + srow) * 512 + (kg & 511);
      #pragma unroll
      for (int i = 0; i < 4; ++i) *(float4*)&av[4 * i] = ((const float4*)ap)[i];
    } else {
      const float* ap = A + (size_t)(bm0 + srow) * K + kg;
      #pragma unroll
      for (int i = 0; i < 4; ++i) *(float4*)&av[4 * i] = ((const float4*)ap)[i];
    }
    {
      const float* bp = B + (size_t)(bn0 + srow) * K + kg;
      #pragma unroll
      for (int i = 0; i < 4; ++i) *(float4*)&bv[4 * i] = ((const float4*)bp)[i];
    }
    unsigned int pa[8], pb[8];
    #pragma unroll
    for (int i = 0; i < 8; ++i) {
      pa[i] = pack_bf16(av[2 * i], av[2 * i + 1]);
      pb[i] = pack_bf16(bv[2 * i], bv[2 * i + 1]);
    }
    unsigned short* adst = &AL[srow * 40 + sk];
    unsigned short* bdst = &BL[srow * 40 + sk];
    *(uint4*)adst       = *(uint4*)&pa[0];
    *(uint4*)(adst + 8) = *(uint4*)&pa[4];
    *(uint4*)bdst       = *(uint4*)&pb[0];
    *(uint4*)(bdst + 8) = *(uint4*)&pb[4];
    __syncthreads();

    short8 af[4], bf[4];
    #pragma unroll
    for (int mi = 0; mi < 4; ++mi)
      af[mi] = *(const short8*)&AL[(wm0 + mi * 16 + lrow) * 40 + lk];
    #pragma unroll
    for (int ni = 0; ni < 4; ++ni)
      bf[ni] = *(const short8*)&BL[(wn0 + ni * 16 + lrow) * 40 + lk];
    #pragma unroll
    for (int mi = 0; mi < 4; ++mi)
      #pragma unroll
      for (int ni = 0; ni < 4; ++ni)
        acc[mi][ni] = __builtin_amdgcn_mfma_f32_16x16x32_bf16(
            af[mi], bf[ni], acc[mi][ni], 0, 0, 0);
    __syncthreads();
  }

  #pragma unroll
  for (int mi = 0; mi < 4; ++mi) {
    #pragma unroll
    for (int ni = 0; ni < 4; ++ni) {
      const int n = bn0 + wn0 + ni * 16 + (lane & 15);
      const float bz = bias[n];
      #pragma unroll
      for (int r = 0; r < 4; ++r) {
        const int m = bm0 + wm0 + mi * 16 + (lane >> 4) * 4 + r;
        float v = acc[mi][ni][r] + bz;
        if (ACT) v = tanhf(v);
        C[(size_t)m * N + n] = v;
      }
    }
  }
}

// ---------------- fused bidirectional scan (r7 sync + in-kernel x2h)
// grid = 64 blocks x 512 thr: dir = bid&1, wg = bid>>1 (16 units/WG).
// thread (row8=tid>>3, klane=tid&7): gate row R = g*512+wg*16+u.
// W_hh slice fp32 in wreg[64]; W_ih slice packed bf16 in wih[KS/2] (KS=K_IN/8).
// u[p] staged 2 steps ahead into swizzled LDS (chunk stride KS+4, conflict-free).
// Ring: 4 replicas x 2 slots x 512 tagged words (unchanged r7 protocol).
template <int K_IN, int SPLIT>
__global__ __launch_bounds__(512) void scan_fused_kernel(
    const float* __restrict__ U1, const float* __restrict__ U2,
    const float* __restrict__ Wih,   // [2][2048][K_IN]
    const float* __restrict__ bias,  // [2][2048]
    const float* __restrict__ Whh,   // [2][2048][512]
    unsigned long long* __restrict__ Tf, unsigned long long* __restrict__ Tb,
    float* __restrict__ Hf, float* __restrict__ Hb)
{
  constexpr int KS = K_IN / 8;     // per-thread Wih k-slice
  constexpr int UP = KS + 4;       // padded chunk stride (floats)
  __shared__ float lds_h[2][576];  // logical j at j + (j>>5)*4
  __shared__ float uL[2][8 * UP];
  const int tid = threadIdx.x;
  const int dir = blockIdx.x & 1;
  const int wg  = blockIdx.x >> 1;
  const float* Wh = Whh + (size_t)dir * 2048 * 512;
  const float* Wx = Wih + (size_t)dir * 2048 * K_IN;
  const float* bs = bias + (size_t)dir * 2048;
  unsigned long long* T = dir ? Tb : Tf;
  float* Hd = dir ? Hb : Hf;

  const int row8 = tid >> 3;
  const int klane = tid & 7;
  const int u = row8 >> 2, g = row8 & 3;
  const int R = g * 512 + wg * 16 + u;

  float wreg[64];
  {
    const float* wrow = Wh + (size_t)R * 512 + klane * 64;
    #pragma unroll
    for (int i = 0; i < 16; ++i) {
      float4 v = ((const float4*)wrow)[i];
      wreg[4 * i] = v.x; wreg[4 * i + 1] = v.y; wreg[4 * i + 2] = v.z; wreg[4 * i + 3] = v.w;
    }
  }
  unsigned int wih[KS / 2];
  {
    const float* wr = Wx + (size_t)R * K_IN + klane * KS;
    #pragma unroll
    for (int j = 0; j < KS / 2; ++j) wih[j] = pack_bf16(wr[2 * j], wr[2 * j + 1]);
  }
  const float bz = (klane == 0) ? bs[R] : 0.f;

  const int l0 = 72 * klane;
  const int l1 = l0 + 36;
  const int la = tid + ((tid >> 5) << 2);
  const int rep = wg & 3;

  // u load/store helpers (thread tid owns logical k = 2*tid .. +1)
  auto loadU = [&](int p) -> float2 {
    float2 r = {0.f, 0.f};
    if (SPLIT) {
      if (tid < 256) r = *(const float2*)&U1[(size_t)p * 512 + 2 * tid];
      else           r = *(const float2*)&U2[(size_t)p * 512 + 2 * (tid - 256)];
    } else if (tid < K_IN / 2) {
      r = *(const float2*)&U1[(size_t)p * K_IN + 2 * tid];
    }
    return r;
  };
  auto storeU = [&](float2 v, int buf) {
    if (SPLIT || tid < K_IN / 2) {
      const int k = 2 * tid;
      const int pos = k + (k / KS) * 4;
      uL[buf][pos] = v.x;
      uL[buf][pos + 1] = v.y;
    }
  };

  for (int i = tid; i < 576; i += 512) lds_h[0][i] = 0.f;
  { float2 v0 = loadU(dir ? NPOS - 1 : 0); storeU(v0, 0); }
  float2 regU = loadU(dir ? NPOS - 2 : 1);
  float creg = 0.f;
  __syncthreads();

  for (int s = 0; s < NPOS; ++s) {
    const int p = dir ? (NPOS - 1 - s) : s;

    // ---- xpart = bias + Wih[R][klane slice] . u[p]  (independent of h)
    const float* ub = &uL[s & 1][klane * UP];
    float xp = bz, xq = 0.f;
    #pragma unroll
    for (int j = 0; j < KS / 4; ++j) {
      float4 a = *(const float4*)&ub[4 * j];
      const unsigned int w0 = wih[2 * j], w1 = wih[2 * j + 1];
      xp = fmaf(__uint_as_float(w0 << 16), a.x, xp);
      xq = fmaf(__uint_as_float(w0 & 0xffff0000u), a.y, xq);
      xp = fmaf(__uint_as_float(w1 << 16), a.z, xp);
      xq = fmaf(__uint_as_float(w1 & 0xffff0000u), a.w, xq);
    }

    // ---- poll h(s-1): one tagged word per thread (r7 protocol)
    if (s > 0) {
      const unsigned int tg = (unsigned int)s;
      const unsigned long long* w =
          T + (size_t)((rep << 1) | ((s - 1) & 1)) * 512 + tid;
      unsigned long long v;
      do { v = __hip_atomic_load(w, __ATOMIC_RELAXED, __HIP_MEMORY_SCOPE_AGENT); }
      while ((unsigned int)(v >> 32) != tg);
      lds_h[s & 1][la] = __uint_as_float((unsigned int)v);
    }
    if (s + 1 < NPOS) storeU(regU, (s + 1) & 1);   // u for step s+1
    __syncthreads();

    // ---- gate sum: xpart + Whh . h
    const float* hb = &lds_h[s & 1][0];
    float sA = xp, sB = xq, sC = 0.f, sD = 0.f;
    #pragma unroll
    for (int i = 0; i < 4; ++i) {
      float4 a = *(const float4*)&hb[l0 + 4 * i];
      sA = fmaf(wreg[4 * i + 0], a.x, sA);
      sA = fmaf(wreg[4 * i + 1], a.y, sA);
      sA = fmaf(wreg[4 * i + 2], a.z, sA);
      sA = fmaf(wreg[4 * i + 3], a.w, sA);
      float4 b = *(const float4*)&hb[l0 + 16 + 4 * i];
      sB = fmaf(wreg[16 + 4 * i + 0], b.x, sB);
      sB = fmaf(wreg[16 + 4 * i + 1], b.y, sB);
      sB = fmaf(wreg[16 + 4 * i + 2], b.z, sB);
      sB = fmaf(wreg[16 + 4 * i + 3], b.w, sB);
      float4 c = *(const float4*)&hb[l1 + 4 * i];
      sC = fmaf(wreg[32 + 4 * i + 0], c.x, sC);
      sC = fmaf(wreg[32 + 4 * i + 1], c.y, sC);
      sC = fmaf(wreg[32 + 4 * i + 2], c.z, sC);
      sC = fmaf(wreg[32 + 4 * i + 3], c.w, sC);
      float4 d = *(const float4*)&hb[l1 + 16 + 4 * i];
      sD = fmaf(wreg[48 + 4 * i + 0], d.x, sD);
      sD = fmaf(wreg[48 + 4 * i + 1], d.y, sD);
      sD = fmaf(wreg[48 + 4 * i + 2], d.z, sD);
      sD = fmaf(wreg[48 + 4 * i + 3], d.w, sD);
    }
    float sum = (sA + sB) + (sC + sD);
    sum += __shfl_xor(sum, 1);
    sum += __shfl_xor(sum, 2);
    sum += __shfl_xor(sum, 4);
    const int base = (tid & 63) & ~31;
    float gf = __shfl(sum, base + 8);
    float gg = __shfl(sum, base + 16);
    float go = __shfl(sum, base + 24);
    if ((tid & 31) == 0) {
      float iv = sigf(sum), fv = sigf(gf), gv = tanh_fast(gg), ov = sigf(go);
      creg = fv * creg + iv * gv;
      float h = ov * tanh_fast(creg);
      const int j = wg * 16 + u;
      unsigned long long pack = ((unsigned long long)(unsigned int)(s + 1) << 32)
                              | (unsigned long long)__float_as_uint(h);
      #pragma unroll
      for (int r2 = 0; r2 < 4; ++r2)
        __hip_atomic_store(&T[(size_t)((r2 << 1) | (s & 1)) * 512 + j], pack,
                           __ATOMIC_RELAXED, __HIP_MEMORY_SCOPE_AGENT);
      Hd[(size_t)p * 512 + j] = h;
    }
    // ---- prefetch u for step s+2 (consumed ~1.6us later)
    if (s + 2 < NPOS) regU = loadU(dir ? NPOS - 3 - s : s + 2);
  }
}

extern "C" void kernel_launch(void* const* d_in, const int* in_sizes, int n_in,
                              void* d_out, int out_size, void* d_ws, size_t ws_size,
                              hipStream_t stream) {
  const int* chars = (const int*)d_in[0];
  const int* lens = (const int*)d_in[1];
  const float* table = (const float*)d_in[2];
  const float* cWih = (const float*)d_in[3];
  const float* cWhh = (const float*)d_in[4];
  const float* cb = (const float*)d_in[5];
  const float* Wih0 = (const float*)d_in[6];   // [2][2048][256]
  const float* Whh0 = (const float*)d_in[7];   // [2][2048][512]
  const float* b0 = (const float*)d_in[8];     // [2][2048]
  const float* Wih1 = (const float*)d_in[9];   // [2][2048][1024]
  const float* Whh1 = (const float*)d_in[10];  // [2][2048][512]
  const float* b1 = (const float*)d_in[11];
  const float* fc1w = (const float*)d_in[12];
  const float* fc1b = (const float*)d_in[13];
  const float* fc2w = (const float*)d_in[14];
  const float* fc2b = (const float*)d_in[15];
  float* out = (float*)d_out;

  char* ws = (char*)d_ws;
  size_t off = 0;
  auto alloc = [&](size_t bytes) -> void* {
    void* p = ws + off;
    off += (bytes + 255) & ~(size_t)255;
    return p;
  };
  float* word_emb = (float*)alloc((size_t)4096 * 256 * 4);
  float* H0f = (float*)alloc((size_t)4096 * 512 * 4);
  float* H0b = (float*)alloc((size_t)4096 * 512 * 4);
  float* H1f = (float*)alloc((size_t)4096 * 512 * 4);
  float* H1b = (float*)alloc((size_t)4096 * 512 * 4);
  float* fc1out = (float*)alloc((size_t)4096 * 512 * 4);
  unsigned int* Wc = (unsigned int*)alloc((size_t)1024 * 512 * 2);   // bf16 [1024][512]
  // 4 rings x (4 replicas x 2 slots x 512 words) x 8B = 512 KB
  unsigned long long* Tall = (unsigned long long*)alloc((size_t)4 * 4096 * 8);
  unsigned long long* T0f = Tall;
  unsigned long long* T0b = Tall + 4096;
  unsigned long long* T1f = Tall + 8192;
  unsigned long long* T1b = Tall + 12288;
  if (off > ws_size) return;

  // clear tag rings (inside graph -> every replay re-synchronizes honestly)
  hipMemsetAsync(Tall, 0, (size_t)4 * 4096 * 8, stream);

  build_wc_kernel<<<1024, 256, 0, stream>>>(cWih, cWhh, Wc);
  mfchar_kernel<<<128, 256, 0, stream>>>(chars, lens, table,
                                         (const unsigned short*)Wc, cb, word_emb);

  scan_fused_kernel<256, 0><<<64, 512, 0, stream>>>(
      word_emb, nullptr, Wih0, b0, Whh0, T0f, T0b, H0f, H0b);
  scan_fused_kernel<1024, 1><<<64, 512, 0, stream>>>(
      H0f, H0b, Wih1, b1, Whh1, T1f, T1b, H1f, H1b);

  mfgemm_kernel<1, 1><<<dim3(32, 4), 256, 0, stream>>>(
      H1f, H1b, fc1w, fc1b, fc1out, 4096, 512, 1024);
  gemm_kernel<0, 0><<<dim3(32, 1), 256, 0, stream>>>(
      fc1out, nullptr, fc2w, fc2b, out, 4096, 50, 512);
}

// Round 13
// 13874.495 us; speedup vs baseline: 2.6692x; 2.6692x over previous
//
#include <hip/hip_runtime.h>
#include <math.h>
#include <stdint.h>

// BiLSTMModel: char-LSTM (MFMA bf16) -> 2x BiLSTM scans (latency-bound) -> FCs.
// r13 = r11 (proven 13.94ms) with mfchar widened: 256 blocks x 16 words
// (2x CU parallelism, half per-block MFMA work). Scan v7 agent-ring and
// mfgemm/gemm byte-identical to r11. r12's fused-x2h reverted (VGPR spill).

#define NPOS 4096
#define GDIM 2048   // 4*H

typedef short short8 __attribute__((ext_vector_type(8)));
typedef float f32x4 __attribute__((ext_vector_type(4)));

__device__ __forceinline__ float sigf(float x) { return 1.0f / (1.0f + __expf(-x)); }
__device__ __forceinline__ float tanh_fast(float x) {
  float e = __expf(2.f * x);
  return 1.f - 2.f / (e + 1.f);   // exact at +-inf, NaN-free
}
__device__ __forceinline__ unsigned int pack_bf16(float a, float b) {
  unsigned int ua = __float_as_uint(a), ub = __float_as_uint(b);
  ua = (ua + 0x7fffu + ((ua >> 16) & 1u)) >> 16;   // RNE
  ub = (ub + 0x7fffu + ((ub >> 16) & 1u)) >> 16;
  return ua | (ub << 16);
}
__device__ __forceinline__ unsigned short bf16_1(float a) {
  unsigned int ua = __float_as_uint(a);
  return (unsigned short)((ua + 0x7fffu + ((ua >> 16) & 1u)) >> 16);
}
__device__ __forceinline__ float bf2f(unsigned short s) {
  return __uint_as_float(((unsigned int)s) << 16);
}

// ---------------- build concat char weight, bf16: Wc[g][k] (g<1024, k<512)
__global__ __launch_bounds__(256) void build_wc_kernel(
    const float* __restrict__ cWih, const float* __restrict__ cWhh,
    unsigned int* __restrict__ Wc)   // as u32 bf16-pairs: [1024][256]
{
  const int idx = blockIdx.x * 256 + threadIdx.x;
  const int g = idx >> 8;
  const int k = (idx & 255) * 2;
  const float* src = (k < 256) ? (cWih + (size_t)g * 256 + k)
                               : (cWhh + (size_t)g * 256 + (k - 256));
  Wc[idx] = pack_bf16(src[0], src[1]);
}

// ---------------- char LSTM v4 (MFMA): 256 blocks x 16 words, 256 thr
// uL: bf16 [16 w][520]: k<256 = emb(t), k in [256,512) = h(t-1).
// Wave v computes gate type v (cols [v*256, v*256+256)) for all 16 words.
// Recombine: thread t = unit t, updates c[w] (w=0..15), writes h + word_emb.
__global__ __launch_bounds__(256) void mfchar_kernel(
    const int* __restrict__ chars, const int* __restrict__ lens,
    const float* __restrict__ table, const unsigned short* __restrict__ Wc,
    const float* __restrict__ cb, float* __restrict__ word_emb)
{
  __shared__ unsigned short uL[16][520];
  __shared__ unsigned short gL[16][1032];
  __shared__ int sidx[16];
  const int tid = threadIdx.x;
  const int lane = tid & 63;
  const int wv = tid >> 6;              // wave id == gate type
  const int w0 = blockIdx.x * 16;
  if (tid < 16) { int l = lens[w0 + tid]; sidx[tid] = (l < 1 ? 1 : l) - 1; }
  for (int i = tid; i < 16 * 256; i += 256) uL[i >> 8][256 + (i & 255)] = 0;

  float bz[16];
  #pragma unroll
  for (int ni = 0; ni < 16; ++ni) bz[ni] = cb[wv * 256 + ni * 16 + (lane & 15)];

  float c[16];
  #pragma unroll
  for (int w = 0; w < 16; ++w) c[w] = 0.f;

  const int arow = lane & 15;
  const int akk = (lane >> 4) * 8;

  for (int t = 0; t < 16; ++t) {
    for (int w = 0; w < 16; ++w) {
      const int cid = chars[(w0 + w) * 16 + t];
      uL[w][tid] = bf16_1(table[(size_t)cid * 256 + tid]);
    }
    __syncthreads();

    // gates[16][256*wv..] = u[16][512] @ Wc[cols][512]^T + bias
    f32x4 acc[16];
    #pragma unroll
    for (int ni = 0; ni < 16; ++ni)
      acc[ni] = (f32x4){bz[ni], bz[ni], bz[ni], bz[ni]};
    for (int kt = 0; kt < 16; ++kt) {
      short8 af0 = *(const short8*)&uL[arow][kt * 32 + akk];
      #pragma unroll
      for (int ni = 0; ni < 16; ++ni) {
        const unsigned short* bp =
            Wc + (size_t)(wv * 256 + ni * 16 + arow) * 512 + kt * 32 + akk;
        short8 bf = *(const short8*)bp;
        acc[ni] = __builtin_amdgcn_mfma_f32_16x16x32_bf16(af0, bf, acc[ni], 0, 0, 0);
      }
    }
    // C/D layout: col = lane&15, row = (lane>>4)*4 + r  [validated r10/r11]
    #pragma unroll
    for (int ni = 0; ni < 16; ++ni) {
      const int col = wv * 256 + ni * 16 + (lane & 15);
      #pragma unroll
      for (int r = 0; r < 4; ++r) {
        const int row = (lane >> 4) * 4 + r;
        gL[row][col] = bf16_1(acc[ni][r]);
      }
    }
    __syncthreads();

    const int j = tid;
    #pragma unroll 4
    for (int w = 0; w < 16; ++w) {
      const float iv = sigf(bf2f(gL[w][j]));
      const float fv = sigf(bf2f(gL[w][256 + j]));
      const float gv = tanh_fast(bf2f(gL[w][512 + j]));
      const float ov = sigf(bf2f(gL[w][768 + j]));
      c[w] = fv * c[w] + iv * gv;
      const float h = ov * tanh_fast(c[w]);
      uL[w][256 + j] = bf16_1(h);
      if (t == sidx[w]) word_emb[(size_t)(w0 + w) * 256 + j] = h;
    }
    __syncthreads();
  }
}

// ---------------- fp32 GEMM (fc2 only): C = A @ B^T + bias
#define SW(c) ((c) + (((c) >> 3) << 2))
template <int SPLIT, int ACT>
__global__ __launch_bounds__(256) void gemm_kernel(
    const float* __restrict__ A, const float* __restrict__ A2,
    const float* __restrict__ B, const float* __restrict__ bias,
    float* __restrict__ C, int M, int N, int K)
{
  __shared__ float At[8 * 192];
  __shared__ float Bt[8 * 192];
  const int tid = threadIdx.x;
  const int bm0 = blockIdx.x * 128, bn0 = blockIdx.y * 128;
  float acc[8][8];
  #pragma unroll
  for (int i = 0; i < 8; ++i)
    #pragma unroll
    for (int j = 0; j < 8; ++j) acc[i][j] = 0.f;
  const int sr = tid >> 1;
  const int sk = (tid & 1) * 4;
  const int tm = (tid >> 4) * 8, tn = (tid & 15) * 8;
  const int swsr = SW(sr);
  const int stm = SW(tm), stn = SW(tn);
  for (int k0 = 0; k0 < K; k0 += 8) {
    const int kg = k0 + sk;
    float4 av;
    if (SPLIT) {
      const float* srcp = (kg < 512) ? A : A2;
      av = *(const float4*)(srcp + (size_t)(bm0 + sr) * 512 + (kg & 511));
    } else {
      av = *(const float4*)(A + (size_t)(bm0 + sr) * K + kg);
    }
    float4 bv = {0.f, 0.f, 0.f, 0.f};
    if (bn0 + sr < N) bv = *(const float4*)(B + (size_t)(bn0 + sr) * K + kg);
    At[(sk + 0) * 192 + swsr] = av.x; At[(sk + 1) * 192 + swsr] = av.y;
    At[(sk + 2) * 192 + swsr] = av.z; At[(sk + 3) * 192 + swsr] = av.w;
    Bt[(sk + 0) * 192 + swsr] = bv.x; Bt[(sk + 1) * 192 + swsr] = bv.y;
    Bt[(sk + 2) * 192 + swsr] = bv.z; Bt[(sk + 3) * 192 + swsr] = bv.w;
    __syncthreads();
    #pragma unroll
    for (int kk = 0; kk < 8; ++kk) {
      float a[8], b[8];
      *(float4*)&a[0] = *(const float4*)&At[kk * 192 + stm];
      *(float4*)&a[4] = *(const float4*)&At[kk * 192 + stm + 4];
      *(float4*)&b[0] = *(const float4*)&Bt[kk * 192 + stn];
      *(float4*)&b[4] = *(const float4*)&Bt[kk * 192 + stn + 4];
      #pragma unroll
      for (int i = 0; i < 8; ++i)
        #pragma unroll
        for (int j = 0; j < 8; ++j) acc[i][j] = fmaf(a[i], b[j], acc[i][j]);
    }
    __syncthreads();
  }
  #pragma unroll
  for (int i = 0; i < 8; ++i) {
    const int m = bm0 + tm + i;
    float* crow = C + (size_t)m * N;
    #pragma unroll
    for (int j = 0; j < 8; ++j) {
      const int n = bn0 + tn + j;
      if (n < N) {
        float v = acc[i][j] + bias[n];
        if (ACT) v = tanhf(v);
        crow[n] = v;
      }
    }
  }
}

// ---------------- MFMA bf16 GEMM (validated r10): C = act(A @ B^T + bias)
// PERM=1: write col n at permuted position (n&511)*4 + (n>>9)  (unit-major x).
template <int SPLIT, int ACT, int PERM>
__global__ __launch_bounds__(256) void mfgemm_kernel(
    const float* __restrict__ A, const float* __restrict__ A2,
    const float* __restrict__ B, const float* __restrict__ bias,
    float* __restrict__ C, int M, int N, int K)
{
  __shared__ unsigned short AL[128 * 40];
  __shared__ unsigned short BL[128 * 40];
  const int tid = threadIdx.x;
  const int bm0 = blockIdx.x * 128, bn0 = blockIdx.y * 128;
  const int srow = tid >> 1;
  const int sk = (tid & 1) * 16;
  const int lane = tid & 63;
  const int wid = tid >> 6;
  const int wm0 = (wid >> 1) * 64;
  const int wn0 = (wid & 1) * 64;
  const int lrow = lane & 15;
  const int lk = (lane >> 4) * 8;

  f32x4 acc[4][4];
  #pragma unroll
  for (int i = 0; i < 4; ++i)
    #pragma unroll
    for (int j = 0; j < 4; ++j) acc[i][j] = (f32x4){0.f, 0.f, 0.f, 0.f};

  for (int k0 = 0; k0 < K; k0 += 32) {
    const int kg = k0 + sk;
    float av[16], bv[16];
    if (SPLIT) {
      const float* srcp = (kg < 512) ? A : A2;
      const float* ap = srcp + (size_t)(bm0 + srow) * 512 + (kg & 511);
      #pragma unroll
      for (int i = 0; i < 4; ++i) *(float4*)&av[4 * i] = ((const float4*)ap)[i];
    } else {
      const float* ap = A + (size_t)(bm0 + srow) * K + kg;
      #pragma unroll
      for (int i = 0; i < 4; ++i) *(float4*)&av[4 * i] = ((const float4*)ap)[i];
    }
    {
      const float* bp = B + (size_t)(bn0 + srow) * K + kg;
      #pragma unroll
      for (int i = 0; i < 4; ++i) *(float4*)&bv[4 * i] = ((const float4*)bp)[i];
    }
    unsigned int pa[8], pb[8];
    #pragma unroll
    for (int i = 0; i < 8; ++i) {
      pa[i] = pack_bf16(av[2 * i], av[2 * i + 1]);
      pb[i] = pack_bf16(bv[2 * i], bv[2 * i + 1]);
    }
    unsigned short* adst = &AL[srow * 40 + sk];
    unsigned short* bdst = &BL[srow * 40 + sk];
    *(uint4*)adst       = *(uint4*)&pa[0];
    *(uint4*)(adst + 8) = *(uint4*)&pa[4];
    *(uint4*)bdst       = *(uint4*)&pb[0];
    *(uint4*)(bdst + 8) = *(uint4*)&pb[4];
    __syncthreads();

    short8 af[4], bf[4];
    #pragma unroll
    for (int mi = 0; mi < 4; ++mi)
      af[mi] = *(const short8*)&AL[(wm0 + mi * 16 + lrow) * 40 + lk];
    #pragma unroll
    for (int ni = 0; ni < 4; ++ni)
      bf[ni] = *(const short8*)&BL[(wn0 + ni * 16 + lrow) * 40 + lk];
    #pragma unroll
    for (int mi = 0; mi < 4; ++mi)
      #pragma unroll
      for (int ni = 0; ni < 4; ++ni)
        acc[mi][ni] = __builtin_amdgcn_mfma_f32_16x16x32_bf16(
            af[mi], bf[ni], acc[mi][ni], 0, 0, 0);
    __syncthreads();
  }

  #pragma unroll
  for (int mi = 0; mi < 4; ++mi) {
    #pragma unroll
    for (int ni = 0; ni < 4; ++ni) {
      const int n = bn0 + wn0 + ni * 16 + (lane & 15);
      const float bz = bias[n];
      const int nw = PERM ? (((n & 511) << 2) | (n >> 9)) : n;
      #pragma unroll
      for (int r = 0; r < 4; ++r) {
        const int m = bm0 + wm0 + mi * 16 + (lane >> 4) * 4 + r;
        float v = acc[mi][ni][r] + bz;
        if (ACT) v = tanhf(v);
        C[(size_t)m * N + nw] = v;
      }
    }
  }
}

// ---------------- persistent bidirectional scan v7 (proven floor config)
__global__ __launch_bounds__(512) void scan_kernel(
    const float* __restrict__ Xf, const float* __restrict__ Xb,
    const float* __restrict__ Whf, const float* __restrict__ Whb,
    unsigned long long* __restrict__ Tf, unsigned long long* __restrict__ Tb,
    float* __restrict__ Hf, float* __restrict__ Hb)
{
  __shared__ float lds_h[2][576];   // logical j at j + (j>>5)*4
  const int tid = threadIdx.x;
  const int dir = blockIdx.x & 1;
  const int wg  = blockIdx.x >> 1;
  const float* X = dir ? Xb : Xf;
  const float* Wh = dir ? Whb : Whf;
  unsigned long long* T = dir ? Tb : Tf;
  float* Hd = dir ? Hb : Hf;

  const int row8 = tid >> 3;              // 0..63
  const int klane = tid & 7;
  const int u = row8 >> 2, g = row8 & 3;
  const int R = g * 512 + wg * 16 + u;    // gate-major row in [0,2048)

  float wreg[64];
  {
    const float* wrow = Wh + (size_t)R * 512 + klane * 64;
    #pragma unroll
    for (int i = 0; i < 16; ++i) {
      float4 v = ((const float4*)wrow)[i];
      wreg[4 * i] = v.x; wreg[4 * i + 1] = v.y; wreg[4 * i + 2] = v.z; wreg[4 * i + 3] = v.w;
    }
  }
  const int l0 = 72 * klane;
  const int l1 = l0 + 36;
  const int la = tid + ((tid >> 5) << 2);
  const int rep = wg & 3;

  for (int i = tid; i < 576; i += 512) lds_h[0][i] = 0.f;

  const bool xl = (klane == 0);
  const int xoff = wg * 64 + row8;
  float xcur = 0.f, xnxt = 0.f;
  if (xl) {
    xcur = X[(size_t)(dir ? NPOS - 1 : 0) * GDIM + xoff];
    xnxt = X[(size_t)(dir ? NPOS - 2 : 1) * GDIM + xoff];
  }
  float creg = 0.f;
  __syncthreads();

  for (int s = 0; s < NPOS; ++s) {
    const int p = dir ? (NPOS - 1 - s) : s;
    if (s > 0) {
      const unsigned int tg = (unsigned int)s;
      const unsigned long long* w =
          T + (size_t)((rep << 1) | ((s - 1) & 1)) * 512 + tid;
      unsigned long long v;
      do { v = __hip_atomic_load(w, __ATOMIC_RELAXED, __HIP_MEMORY_SCOPE_AGENT); }
      while ((unsigned int)(v >> 32) != tg);
      lds_h[s & 1][la] = __uint_as_float((unsigned int)v);
    }
    __syncthreads();
    const float* hb = &lds_h[s & 1][0];
    float sA = xl ? xcur : 0.f, sB = 0.f, sC = 0.f, sD = 0.f;
    if (xl) {
      xcur = xnxt;
      if (s + 2 < NPOS) xnxt = X[(size_t)(dir ? NPOS - 3 - s : s + 2) * GDIM + xoff];
    }
    #pragma unroll
    for (int i = 0; i < 4; ++i) {
      float4 a = *(const float4*)&hb[l0 + 4 * i];
      sA = fmaf(wreg[4 * i + 0], a.x, sA);
      sA = fmaf(wreg[4 * i + 1], a.y, sA);
      sA = fmaf(wreg[4 * i + 2], a.z, sA);
      sA = fmaf(wreg[4 * i + 3], a.w, sA);
      float4 b = *(const float4*)&hb[l0 + 16 + 4 * i];
      sB = fmaf(wreg[16 + 4 * i + 0], b.x, sB);
      sB = fmaf(wreg[16 + 4 * i + 1], b.y, sB);
      sB = fmaf(wreg[16 + 4 * i + 2], b.z, sB);
      sB = fmaf(wreg[16 + 4 * i + 3], b.w, sB);
      float4 c = *(const float4*)&hb[l1 + 4 * i];
      sC = fmaf(wreg[32 + 4 * i + 0], c.x, sC);
      sC = fmaf(wreg[32 + 4 * i + 1], c.y, sC);
      sC = fmaf(wreg[32 + 4 * i + 2], c.z, sC);
      sC = fmaf(wreg[32 + 4 * i + 3], c.w, sC);
      float4 d = *(const float4*)&hb[l1 + 16 + 4 * i];
      sD = fmaf(wreg[48 + 4 * i + 0], d.x, sD);
      sD = fmaf(wreg[48 + 4 * i + 1], d.y, sD);
      sD = fmaf(wreg[48 + 4 * i + 2], d.z, sD);
      sD = fmaf(wreg[48 + 4 * i + 3], d.w, sD);
    }
    float sum = (sA + sB) + (sC + sD);
    sum += __shfl_xor(sum, 1);
    sum += __shfl_xor(sum, 2);
    sum += __shfl_xor(sum, 4);
    const int base = (tid & 63) & ~31;
    float gf = __shfl(sum, base + 8);
    float gg = __shfl(sum, base + 16);
    float go = __shfl(sum, base + 24);
    if ((tid & 31) == 0) {
      float iv = sigf(sum), fv = sigf(gf), gv = tanh_fast(gg), ov = sigf(go);
      creg = fv * creg + iv * gv;
      float h = ov * tanh_fast(creg);
      const int j = wg * 16 + u;
      unsigned long long pack = ((unsigned long long)(unsigned int)(s + 1) << 32)
                              | (unsigned long long)__float_as_uint(h);
      #pragma unroll
      for (int r2 = 0; r2 < 4; ++r2)
        __hip_atomic_store(&T[(size_t)((r2 << 1) | (s & 1)) * 512 + j], pack,
                           __ATOMIC_RELAXED, __HIP_MEMORY_SCOPE_AGENT);
      Hd[(size_t)p * 512 + j] = h;
    }
  }
}

extern "C" void kernel_launch(void* const* d_in, const int* in_sizes, int n_in,
                              void* d_out, int out_size, void* d_ws, size_t ws_size,
                              hipStream_t stream) {
  const int* chars = (const int*)d_in[0];
  const int* lens = (const int*)d_in[1];
  const float* table = (const float*)d_in[2];
  const float* cWih = (const float*)d_in[3];
  const float* cWhh = (const float*)d_in[4];
  const float* cb = (const float*)d_in[5];
  const float* Wih0 = (const float*)d_in[6];   // [2][2048][256]
  const float* Whh0 = (const float*)d_in[7];   // [2][2048][512]
  const float* b0 = (const float*)d_in[8];
  const float* Wih1 = (const float*)d_in[9];   // [2][2048][1024]
  const float* Whh1 = (const float*)d_in[10];  // [2][2048][512]
  const float* b1 = (const float*)d_in[11];
  const float* fc1w = (const float*)d_in[12];
  const float* fc1b = (const float*)d_in[13];
  const float* fc2w = (const float*)d_in[14];
  const float* fc2b = (const float*)d_in[15];
  float* out = (float*)d_out;

  char* ws = (char*)d_ws;
  size_t off = 0;
  auto alloc = [&](size_t bytes) -> void* {
    void* p = ws + off;
    off += (bytes + 255) & ~(size_t)255;
    return p;
  };
  float* word_emb = (float*)alloc((size_t)4096 * 256 * 4);
  float* X0f = (float*)alloc((size_t)4096 * 2048 * 4);
  float* X0b = (float*)alloc((size_t)4096 * 2048 * 4);
  float* H0f = (float*)alloc((size_t)4096 * 512 * 4);
  float* H0b = (float*)alloc((size_t)4096 * 512 * 4);
  float* H1f = (float*)alloc((size_t)4096 * 512 * 4);
  float* H1b = (float*)alloc((size_t)4096 * 512 * 4);
  float* fc1out = (float*)alloc((size_t)4096 * 512 * 4);
  unsigned int* Wc = (unsigned int*)alloc((size_t)1024 * 512 * 2);   // bf16 [1024][512]
  // 4 rings x (4 replicas x 2 slots x 512 words) x 8B = 512 KB
  unsigned long long* Tall = (unsigned long long*)alloc((size_t)4 * 4096 * 8);
  unsigned long long* T0f = Tall;
  unsigned long long* T0b = Tall + 4096;
  unsigned long long* T1f = Tall + 8192;
  unsigned long long* T1b = Tall + 12288;
  if (off > ws_size) return;

  // clear tag rings (inside graph -> every replay re-synchronizes honestly)
  hipMemsetAsync(Tall, 0, (size_t)4 * 4096 * 8, stream);

  build_wc_kernel<<<1024, 256, 0, stream>>>(cWih, cWhh, Wc);
  mfchar_kernel<<<256, 256, 0, stream>>>(chars, lens, table,
                                         (const unsigned short*)Wc, cb, word_emb);

  mfgemm_kernel<0, 0, 1><<<dim3(32, 16), 256, 0, stream>>>(
      word_emb, nullptr, Wih0, b0, X0f, 4096, 2048, 256);
  mfgemm_kernel<0, 0, 1><<<dim3(32, 16), 256, 0, stream>>>(
      word_emb, nullptr, Wih0 + (size_t)2048 * 256, b0 + 2048, X0b, 4096, 2048, 256);
  scan_kernel<<<64, 512, 0, stream>>>(X0f, X0b, Whh0, Whh0 + (size_t)2048 * 512,
                                      T0f, T0b, H0f, H0b);

  mfgemm_kernel<1, 0, 1><<<dim3(32, 16), 256, 0, stream>>>(
      H0f, H0b, Wih1, b1, X0f, 4096, 2048, 1024);
  mfgemm_kernel<1, 0, 1><<<dim3(32, 16), 256, 0, stream>>>(
      H0f, H0b, Wih1 + (size_t)2048 * 1024, b1 + 2048, X0b, 4096, 2048, 1024);
  scan_kernel<<<64, 512, 0, stream>>>(X0f, X0b, Whh1, Whh1 + (size_t)2048 * 512,
                                      T1f, T1b, H1f, H1b);

  mfgemm_kernel<1, 1, 0><<<dim3(32, 4), 256, 0, stream>>>(
      H1f, H1b, fc1w, fc1b, fc1out, 4096, 512, 1024);
  gemm_kernel<0, 0><<<dim3(32, 1), 256, 0, stream>>>(
      fc1out, nullptr, fc2w, fc2b, out, 4096, 50, 512);
}